// Round 3
// baseline (64.793 us; speedup 1.0000x reference)
//
#include <hip/hip_runtime.h>

#define NU 8192
#define NI 8192
#define DM 32
#define KC 32
#define HEADS 4
#define HK 8
#define BIASV 0.1f

#define NBLK 256      // == CU count -> all blocks co-resident, manual grid barrier safe
#define NT 256        // 4 waves/block
#define UBLK 128      // blocks that own users (phase A) / pair-segments (phase B)

// leader-based grid barrier (cooperative-groups pattern). bar zeroed by
// hipMemsetAsync before launch each replay.
__device__ __forceinline__ void grid_barrier(int* bar, int target) {
    __syncthreads();
    if (threadIdx.x == 0) {
        __hip_atomic_fetch_add(bar, 1, __ATOMIC_ACQ_REL, __HIP_MEMORY_SCOPE_AGENT);
        while (__hip_atomic_load(bar, __ATOMIC_ACQUIRE, __HIP_MEMORY_SCOPE_AGENT) < target)
            __builtin_amdgcn_s_sleep(1);
    }
    __syncthreads();
}

__global__ __launch_bounds__(NT) void k_fused(
    const float* __restrict__ U, const float* __restrict__ I,
    const float* __restrict__ Wk, const float* __restrict__ bk,
    const float* __restrict__ Wq, const float* __restrict__ bq,
    const float* __restrict__ Wr, const float* __restrict__ br,
    float* __restrict__ keys, float* __restrict__ q,
    float* __restrict__ part, int* __restrict__ cnt, int* __restrict__ act,
    int* __restrict__ bar, float* __restrict__ out)
{
    __shared__ union {
        struct { float W[DM * KC]; float b[KC]; float wp[4][HEADS][HK]; } a;
        struct { float sinv[KC]; int lcnt; int list[NT]; } bp;
        struct { int scnt[UBLK]; int total; float q_s[32][KC];
                 float agg[32][HEADS * DM]; float Wr_s[HEADS * DM * KC / DM * 8]; } c; // Wr_s[128*32]
    } sm;

    const int blk = blockIdx.x;
    const int t   = threadIdx.x;
    const int g   = blk * NT + t;
    const int row = g >> 2;          // 0..16383 (users then items)
    const int qr  = g & 3;           // channel quarter == head for items
    const bool is_user = (row < NU); // block-uniform (64 rows/block)

    // ---------------- Phase A: embed ----------------
    {
        const float* W  = is_user ? Wk : Wq;
        const float* bb = is_user ? bk : bq;
        for (int i = t; i < DM * KC; i += NT) sm.a.W[i] = W[i];
        if (t < KC) sm.a.b[t] = bb[t];
        __syncthreads();

        const float* Erow = is_user ? (U + row * DM) : (I + (row - NU) * DM);
        float e[DM];
        const float4* ev = (const float4*)Erow;
        #pragma unroll
        for (int j = 0; j < DM / 4; ++j) {
            float4 v = ev[j];
            e[4*j+0] = v.x; e[4*j+1] = v.y; e[4*j+2] = v.z; e[4*j+3] = v.w;
        }
        float o[HK];
        #pragma unroll
        for (int j = 0; j < HK; ++j) {
            float s = sm.a.b[qr * HK + j];
            #pragma unroll
            for (int dd = 0; dd < DM; ++dd) s += e[dd] * sm.a.W[dd * KC + qr * HK + j];
            o[j] = s;
        }

        if (is_user) {
            float4* dst = (float4*)(keys + row * KC + qr * HK);
            dst[0] = make_float4(o[0], o[1], o[2], o[3]);
            dst[1] = make_float4(o[4], o[5], o[6], o[7]);
            float sx[HK];
            #pragma unroll
            for (int j = 0; j < HK; ++j) sx[j] = __expf(o[j]);
            #pragma unroll
            for (int m = 4; m < 64; m <<= 1) {
                #pragma unroll
                for (int j = 0; j < HK; ++j) sx[j] += __shfl_xor(sx[j], m, 64);
            }
            const int lane = t & 63, wv = t >> 6;
            if (lane < 4) {
                #pragma unroll
                for (int j = 0; j < HK; ++j) sm.a.wp[wv][lane][j] = sx[j];
            }
        } else {
            float m = o[0];
            #pragma unroll
            for (int j = 1; j < HK; ++j) m = fmaxf(m, o[j]);
            float sum = 0.f;
            #pragma unroll
            for (int j = 0; j < HK; ++j) { float tt = __expf(o[j] - m); o[j] = tt; sum += tt; }
            float inv = 1.f / sum;
            float4* dst = (float4*)(q + (row - NU) * KC + qr * HK);
            dst[0] = make_float4(o[0]*inv, o[1]*inv, o[2]*inv, o[3]*inv);
            dst[1] = make_float4(o[4]*inv, o[5]*inv, o[6]*inv, o[7]*inv);
        }
        __syncthreads();
        if (is_user && t < KC) {
            const int h = t >> 3, j = t & 7;
            part[blk * KC + t] = sm.a.wp[0][h][j] + sm.a.wp[1][h][j]
                               + sm.a.wp[2][h][j] + sm.a.wp[3][h][j];
        }
    }

    grid_barrier(bar, NBLK);

    // ---------------- Phase B: normalize keys + activity compaction ----------------
    // bound: sum_c k*q <= max_c k (q>=0, sum_c q=1) -> (u,h) inactive if max<=BIAS
    if (blk < UBLK) {
        if (t == 0) sm.bp.lcnt = 0;
        if (t < KC) {
            float s = 0.f;
            #pragma unroll 8
            for (int b2 = 0; b2 < UBLK; ++b2) s += part[b2 * KC + t];
            sm.bp.sinv[t] = 1.f / s;
        }
        __syncthreads();
        const int pg = blk * NT + t;       // pair id == (u<<2)|h, 32 B-coalesced
        const int h  = pg & 3;
        float4* kv = (float4*)(keys + pg * HK);
        float4 v0 = kv[0], v1 = kv[1];
        float kk[HK] = {v0.x, v0.y, v0.z, v0.w, v1.x, v1.y, v1.z, v1.w};
        #pragma unroll
        for (int j = 0; j < HK; ++j) kk[j] = __expf(kk[j]) * sm.bp.sinv[h * HK + j];
        kv[0] = make_float4(kk[0], kk[1], kk[2], kk[3]);
        kv[1] = make_float4(kk[4], kk[5], kk[6], kk[7]);
        float mx = kk[0];
        #pragma unroll
        for (int j = 1; j < HK; ++j) mx = fmaxf(mx, kk[j]);
        if (mx > BIASV) {
            int p = atomicAdd(&sm.bp.lcnt, 1);
            sm.bp.list[p] = pg;
        }
        __syncthreads();
        const int n = sm.bp.lcnt;
        for (int i = t; i < n; i += NT) act[blk * NT + i] = sm.bp.list[i];
        if (t == 0) cnt[blk] = n;
    }

    grid_barrier(bar, 2 * NBLK);

    // ---------------- Phase C: epilogue ----------------
    if (t < UBLK) sm.c.scnt[t] = cnt[t];
    __syncthreads();
    if (t < 64) {
        int v = sm.c.scnt[t] + sm.c.scnt[t + 64];
        #pragma unroll
        for (int m = 1; m < 64; m <<= 1) v += __shfl_xor(v, m, 64);
        if (t == 0) sm.c.total = v;
    }
    __syncthreads();

    if (sm.c.total == 0) {                 // fast path: out = I + br, one float4/thread
        const float4 brv = ((const float4*)br)[g & 7];
        const float4 iv  = ((const float4*)I)[g];
        ((float4*)out)[g] = make_float4(iv.x + brv.x, iv.y + brv.y,
                                        iv.z + brv.z, iv.w + brv.w);
        return;
    }

    // general path: 32 items/block, 8 threads/item, 4 d-channels/thread
    for (int i = t; i < HEADS * DM * KC; i += NT) sm.c.Wr_s[i] = Wr[i];
    const int itbase = blk * 32;
    for (int i = t; i < 32 * KC; i += NT) sm.c.q_s[i >> 5][i & 31] = q[itbase * KC + i];
    __syncthreads();

    const int il  = t >> 3;
    const int sub = t & 7;
    float acc[HEADS][4] = {{0.f}};
    for (int b2 = 0; b2 < UBLK; ++b2) {
        const int n = sm.c.scnt[b2];
        const int* __restrict__ seg = act + b2 * NT;
        for (int p = 0; p < n; ++p) {
            const int pr = seg[p];
            const int u = pr >> 2, h = pr & 3;
            const float* kr = keys + u * KC + h * HK;
            const float* qrow = &sm.c.q_s[il][h * HK];
            float s = 0.f;
            #pragma unroll
            for (int c = 0; c < HK; ++c) s += kr[c] * qrow[c];
            s -= BIASV;
            if (s > 0.f) {
                const float* Ur = U + u * DM + sub * 4;
                #pragma unroll
                for (int jj = 0; jj < 4; ++jj) acc[h][jj] += s * Ur[jj];
            }
        }
    }
    #pragma unroll
    for (int h = 0; h < HEADS; ++h)
        #pragma unroll
        for (int jj = 0; jj < 4; ++jj)
            sm.c.agg[il][h * DM + sub * 4 + jj] = acc[h][jj];
    __syncthreads();

    float r[4];
    #pragma unroll
    for (int cc = 0; cc < 4; ++cc) r[cc] = br[sub * 4 + cc];
    for (int j = 0; j < HEADS * DM; ++j) {
        const float a = sm.c.agg[il][j];
        #pragma unroll
        for (int cc = 0; cc < 4; ++cc) r[cc] += a * sm.c.Wr_s[j * KC + sub * 4 + cc];
    }
    #pragma unroll
    for (int cc = 0; cc < 4; ++cc) {
        const int idx = (itbase + il) * KC + sub * 4 + cc;
        out[idx] = I[idx] + r[cc];
    }
}

extern "C" void kernel_launch(void* const* d_in, const int* in_sizes, int n_in,
                              void* d_out, int out_size, void* d_ws, size_t ws_size,
                              hipStream_t stream) {
    const float* U  = (const float*)d_in[0];
    const float* I  = (const float*)d_in[1];
    const float* Wk = (const float*)d_in[2];
    const float* bk = (const float*)d_in[3];
    const float* Wq = (const float*)d_in[4];
    const float* bq = (const float*)d_in[5];
    const float* Wr = (const float*)d_in[6];
    const float* br = (const float*)d_in[7];
    float* out = (float*)d_out;

    float* ws_keys = (float*)d_ws;                    // NU*KC
    float* ws_q    = ws_keys + NU * KC;               // NI*KC
    float* ws_part = ws_q + NI * KC;                  // UBLK*KC
    int*   ws_cnt  = (int*)(ws_part + UBLK * KC);     // UBLK
    int*   ws_act  = ws_cnt + UBLK;                   // UBLK*NT
    int*   ws_bar  = ws_act + UBLK * NT;              // barrier counter (64B)

    hipMemsetAsync(ws_bar, 0, 64, stream);
    k_fused<<<NBLK, NT, 0, stream>>>(U, I, Wk, bk, Wq, bq, Wr, br,
                                     ws_keys, ws_q, ws_part, ws_cnt, ws_act,
                                     ws_bar, out);
}

// Round 4
// 51.837 us; speedup vs baseline: 1.2499x; 1.2499x over previous
//
#include <hip/hip_runtime.h>

#define NU 8192
#define NI 8192
#define DM 32
#define KC 32
#define HEADS 4
#define HK 8
#define BIASV 0.1f

#define NBLK 256      // == CU count -> all blocks co-resident, manual grid barrier safe
#define NT 256        // 4 waves/block
#define UBLK 128      // blocks that own users (phase A) / pair-segments (phase B)

// Distributed-flag grid barrier. flags[NBLK] zeroed by hipMemsetAsync each replay.
// arrive: one RELEASE store per block (L2 writeback, needed for cross-XCD visibility).
// wait: RELAXED polls (no per-iteration cache invalidates!), one ACQUIRE fence at exit.
__device__ __forceinline__ void grid_barrier(int* flags, int phase) {
    __syncthreads();
    if (threadIdx.x == 0)
        __hip_atomic_store(&flags[blockIdx.x], phase, __ATOMIC_RELEASE, __HIP_MEMORY_SCOPE_AGENT);
    while (__hip_atomic_load(&flags[threadIdx.x], __ATOMIC_RELAXED, __HIP_MEMORY_SCOPE_AGENT) < phase)
        __builtin_amdgcn_s_sleep(1);
    __builtin_amdgcn_fence(__ATOMIC_ACQUIRE, "agent");
    __syncthreads();
}

__global__ __launch_bounds__(NT) void k_fused(
    const float* __restrict__ U, const float* __restrict__ I,
    const float* __restrict__ Wk, const float* __restrict__ bk,
    const float* __restrict__ Wq, const float* __restrict__ bq,
    const float* __restrict__ Wr, const float* __restrict__ br,
    float* __restrict__ keys, float* __restrict__ q,
    float* __restrict__ part, int* __restrict__ cnt, int* __restrict__ act,
    int* __restrict__ flags, float* __restrict__ out)
{
    __shared__ union {
        struct { float W[DM * KC]; float b[KC]; float wp[4][HEADS][HK]; } a;
        struct { float sinv[KC]; float psum[8][KC]; int lcnt; int list[NT]; } bp;
        struct { int scnt[UBLK]; int total; float q_s[32][KC];
                 float agg[32][HEADS * DM]; float Wr_s[HEADS * DM * KC / DM * 8]; } c; // Wr_s[128*32]
    } sm;

    const int blk = blockIdx.x;
    const int t   = threadIdx.x;
    const int g   = blk * NT + t;
    const int row = g >> 2;          // 0..16383 (users then items)
    const int qr  = g & 3;           // channel quarter == head for items
    const bool is_user = (row < NU); // block-uniform (64 rows/block)

    // ---------------- Phase A: embed ----------------
    {
        const float* W  = is_user ? Wk : Wq;
        const float* bb = is_user ? bk : bq;
        for (int i = t; i < DM * KC; i += NT) sm.a.W[i] = W[i];
        if (t < KC) sm.a.b[t] = bb[t];
        __syncthreads();

        const float* Erow = is_user ? (U + row * DM) : (I + (row - NU) * DM);
        float e[DM];
        const float4* ev = (const float4*)Erow;
        #pragma unroll
        for (int j = 0; j < DM / 4; ++j) {
            float4 v = ev[j];
            e[4*j+0] = v.x; e[4*j+1] = v.y; e[4*j+2] = v.z; e[4*j+3] = v.w;
        }
        float o[HK];
        #pragma unroll
        for (int j = 0; j < HK; ++j) {
            float s = sm.a.b[qr * HK + j];
            #pragma unroll
            for (int dd = 0; dd < DM; ++dd) s += e[dd] * sm.a.W[dd * KC + qr * HK + j];
            o[j] = s;
        }

        if (is_user) {
            float4* dst = (float4*)(keys + row * KC + qr * HK);
            dst[0] = make_float4(o[0], o[1], o[2], o[3]);
            dst[1] = make_float4(o[4], o[5], o[6], o[7]);
            float sx[HK];
            #pragma unroll
            for (int j = 0; j < HK; ++j) sx[j] = __expf(o[j]);
            #pragma unroll
            for (int m = 4; m < 64; m <<= 1) {
                #pragma unroll
                for (int j = 0; j < HK; ++j) sx[j] += __shfl_xor(sx[j], m, 64);
            }
            const int lane = t & 63, wv = t >> 6;
            if (lane < 4) {
                #pragma unroll
                for (int j = 0; j < HK; ++j) sm.a.wp[wv][lane][j] = sx[j];
            }
        } else {
            float m = o[0];
            #pragma unroll
            for (int j = 1; j < HK; ++j) m = fmaxf(m, o[j]);
            float sum = 0.f;
            #pragma unroll
            for (int j = 0; j < HK; ++j) { float tt = __expf(o[j] - m); o[j] = tt; sum += tt; }
            float inv = 1.f / sum;
            float4* dst = (float4*)(q + (row - NU) * KC + qr * HK);
            dst[0] = make_float4(o[0]*inv, o[1]*inv, o[2]*inv, o[3]*inv);
            dst[1] = make_float4(o[4]*inv, o[5]*inv, o[6]*inv, o[7]*inv);
        }
        __syncthreads();
        if (is_user && t < KC) {
            const int h = t >> 3, j = t & 7;
            part[blk * KC + t] = sm.a.wp[0][h][j] + sm.a.wp[1][h][j]
                               + sm.a.wp[2][h][j] + sm.a.wp[3][h][j];
        }
    }

    grid_barrier(flags, 1);

    // ---------------- Phase B: normalize keys + activity compaction ----------------
    // bound: sum_c k*q <= max_c k (q>=0, sum_c q=1) -> (u,h) inactive if max<=BIAS
    if (blk < UBLK) {
        if (t == 0) sm.bp.lcnt = 0;
        {   // merge column partials with all 256 threads
            const int c = t & 31, ch = t >> 5;
            float s = 0.f;
            #pragma unroll 4
            for (int b2 = ch; b2 < UBLK; b2 += 8) s += part[b2 * KC + c];
            sm.bp.psum[ch][c] = s;
        }
        __syncthreads();
        if (t < KC) {
            float s = 0.f;
            #pragma unroll
            for (int i = 0; i < 8; ++i) s += sm.bp.psum[i][t];
            sm.bp.sinv[t] = 1.f / s;
        }
        __syncthreads();
        const int pg = blk * NT + t;       // pair id == (u<<2)|h, 32 B-coalesced
        const int h  = pg & 3;
        float4* kv = (float4*)(keys + pg * HK);
        float4 v0 = kv[0], v1 = kv[1];
        float kk[HK] = {v0.x, v0.y, v0.z, v0.w, v1.x, v1.y, v1.z, v1.w};
        #pragma unroll
        for (int j = 0; j < HK; ++j) kk[j] = __expf(kk[j]) * sm.bp.sinv[h * HK + j];
        kv[0] = make_float4(kk[0], kk[1], kk[2], kk[3]);
        kv[1] = make_float4(kk[4], kk[5], kk[6], kk[7]);
        float mx = kk[0];
        #pragma unroll
        for (int j = 1; j < HK; ++j) mx = fmaxf(mx, kk[j]);
        if (mx > BIASV) {
            int p = atomicAdd(&sm.bp.lcnt, 1);
            sm.bp.list[p] = pg;
        }
        __syncthreads();
        const int n = sm.bp.lcnt;
        for (int i = t; i < n; i += NT) act[blk * NT + i] = sm.bp.list[i];
        if (t == 0) cnt[blk] = n;
    }

    grid_barrier(flags, 2);

    // ---------------- Phase C: epilogue ----------------
    if (t < UBLK) sm.c.scnt[t] = cnt[t];
    __syncthreads();
    if (t < 64) {
        int v = sm.c.scnt[t] + sm.c.scnt[t + 64];
        #pragma unroll
        for (int m = 1; m < 64; m <<= 1) v += __shfl_xor(v, m, 64);
        if (t == 0) sm.c.total = v;
    }
    __syncthreads();

    if (sm.c.total == 0) {                 // fast path: out = I + br, one float4/thread
        const float4 brv = ((const float4*)br)[g & 7];
        const float4 iv  = ((const float4*)I)[g];
        ((float4*)out)[g] = make_float4(iv.x + brv.x, iv.y + brv.y,
                                        iv.z + brv.z, iv.w + brv.w);
        return;
    }

    // general path: 32 items/block, 8 threads/item, 4 d-channels/thread
    for (int i = t; i < HEADS * DM * KC; i += NT) sm.c.Wr_s[i] = Wr[i];
    const int itbase = blk * 32;
    for (int i = t; i < 32 * KC; i += NT) sm.c.q_s[i >> 5][i & 31] = q[itbase * KC + i];
    __syncthreads();

    const int il  = t >> 3;
    const int sub = t & 7;
    float acc[HEADS][4] = {{0.f}};
    for (int b2 = 0; b2 < UBLK; ++b2) {
        const int n = sm.c.scnt[b2];
        const int* __restrict__ seg = act + b2 * NT;
        for (int p = 0; p < n; ++p) {
            const int pr = seg[p];
            const int u = pr >> 2, h = pr & 3;
            const float* kr = keys + u * KC + h * HK;
            const float* qrow = &sm.c.q_s[il][h * HK];
            float s = 0.f;
            #pragma unroll
            for (int c = 0; c < HK; ++c) s += kr[c] * qrow[c];
            s -= BIASV;
            if (s > 0.f) {
                const float* Ur = U + u * DM + sub * 4;
                #pragma unroll
                for (int jj = 0; jj < 4; ++jj) acc[h][jj] += s * Ur[jj];
            }
        }
    }
    #pragma unroll
    for (int h = 0; h < HEADS; ++h)
        #pragma unroll
        for (int jj = 0; jj < 4; ++jj)
            sm.c.agg[il][h * DM + sub * 4 + jj] = acc[h][jj];
    __syncthreads();

    float r[4];
    #pragma unroll
    for (int cc = 0; cc < 4; ++cc) r[cc] = br[sub * 4 + cc];
    for (int j = 0; j < HEADS * DM; ++j) {
        const float a = sm.c.agg[il][j];
        #pragma unroll
        for (int cc = 0; cc < 4; ++cc) r[cc] += a * sm.c.Wr_s[j * KC + sub * 4 + cc];
    }
    #pragma unroll
    for (int cc = 0; cc < 4; ++cc) {
        const int idx = (itbase + il) * KC + sub * 4 + cc;
        out[idx] = I[idx] + r[cc];
    }
}

extern "C" void kernel_launch(void* const* d_in, const int* in_sizes, int n_in,
                              void* d_out, int out_size, void* d_ws, size_t ws_size,
                              hipStream_t stream) {
    const float* U  = (const float*)d_in[0];
    const float* I  = (const float*)d_in[1];
    const float* Wk = (const float*)d_in[2];
    const float* bk = (const float*)d_in[3];
    const float* Wq = (const float*)d_in[4];
    const float* bq = (const float*)d_in[5];
    const float* Wr = (const float*)d_in[6];
    const float* br = (const float*)d_in[7];
    float* out = (float*)d_out;

    float* ws_keys = (float*)d_ws;                    // NU*KC
    float* ws_q    = ws_keys + NU * KC;               // NI*KC
    float* ws_part = ws_q + NI * KC;                  // UBLK*KC
    int*   ws_cnt  = (int*)(ws_part + UBLK * KC);     // UBLK
    int*   ws_act  = ws_cnt + UBLK;                   // UBLK*NT
    int*   ws_flags= ws_act + UBLK * NT;              // NBLK flags

    hipMemsetAsync(ws_flags, 0, NBLK * sizeof(int), stream);
    k_fused<<<NBLK, NT, 0, stream>>>(U, I, Wk, bk, Wq, bq, Wr, br,
                                     ws_keys, ws_q, ws_part, ws_cnt, ws_act,
                                     ws_flags, out);
}

// Round 5
// 15.524 us; speedup vs baseline: 4.1737x; 3.3391x over previous
//
#include <hip/hip_runtime.h>

#define NU 8192
#define NI 8192
#define DM 32
#define KC 32
#define HEADS 4
#define HK 8
#define BIASV 0.1f

#define UBLK 128   // user blocks in K1 (64 rows x 4 col-quarters x 256 threads)

// ---- K1: 256 blocks x 256 threads; 4 threads per row, 8 channels each.
// user blocks (0..127): raw keys + per-block column sum(exp) AND column max partials.
// item blocks (128..255): per-head row softmax -> q.
__global__ __launch_bounds__(256) void k_embed(
    const float* __restrict__ U, const float* __restrict__ I,
    const float* __restrict__ Wk, const float* __restrict__ bk,
    const float* __restrict__ Wq, const float* __restrict__ bq,
    float* __restrict__ keys, float* __restrict__ q,
    float* __restrict__ part_s, float* __restrict__ part_m)
{
    __shared__ float Ws[DM * KC];
    __shared__ float bs[KC];
    __shared__ float wps[4][HEADS][HK];   // per-wave col-sum partials
    __shared__ float wpm[4][HEADS][HK];   // per-wave col-max partials

    const int blk = blockIdx.x;
    const int t   = threadIdx.x;
    const int g   = blk * 256 + t;
    const int row = g >> 2;              // 0..16383
    const int qr  = g & 3;               // channel quarter == head
    const bool is_user = (row < NU);     // block-uniform

    const float* W  = is_user ? Wk : Wq;
    const float* bb = is_user ? bk : bq;
    for (int i = t; i < DM * KC; i += 256) Ws[i] = W[i];
    if (t < KC) bs[t] = bb[t];
    __syncthreads();

    const float* Erow = is_user ? (U + row * DM) : (I + (row - NU) * DM);
    float e[DM];
    const float4* ev = (const float4*)Erow;
    #pragma unroll
    for (int j = 0; j < DM / 4; ++j) {
        float4 v = ev[j];
        e[4*j+0] = v.x; e[4*j+1] = v.y; e[4*j+2] = v.z; e[4*j+3] = v.w;
    }
    float o[HK];
    #pragma unroll
    for (int j = 0; j < HK; ++j) {
        float s = bs[qr * HK + j];
        #pragma unroll
        for (int dd = 0; dd < DM; ++dd) s += e[dd] * Ws[dd * KC + qr * HK + j];
        o[j] = s;
    }

    if (is_user) {
        float4* dst = (float4*)(keys + row * KC + qr * HK);
        dst[0] = make_float4(o[0], o[1], o[2], o[3]);
        dst[1] = make_float4(o[4], o[5], o[6], o[7]);
        float sx[HK], mx[HK];
        #pragma unroll
        for (int j = 0; j < HK; ++j) { sx[j] = __expf(o[j]); mx[j] = o[j]; }
        #pragma unroll
        for (int m = 4; m < 64; m <<= 1) {
            #pragma unroll
            for (int j = 0; j < HK; ++j) {
                sx[j] += __shfl_xor(sx[j], m, 64);
                mx[j]  = fmaxf(mx[j], __shfl_xor(mx[j], m, 64));
            }
        }
        const int lane = t & 63, wv = t >> 6;
        if (lane < 4) {
            #pragma unroll
            for (int j = 0; j < HK; ++j) { wps[wv][lane][j] = sx[j]; wpm[wv][lane][j] = mx[j]; }
        }
        __syncthreads();
        if (t < KC) {
            const int h = t >> 3, j = t & 7;
            part_s[blk * KC + t] = wps[0][h][j] + wps[1][h][j] + wps[2][h][j] + wps[3][h][j];
            part_m[blk * KC + t] = fmaxf(fmaxf(wpm[0][h][j], wpm[1][h][j]),
                                         fmaxf(wpm[2][h][j], wpm[3][h][j]));
        }
    } else {
        float m = o[0];
        #pragma unroll
        for (int j = 1; j < HK; ++j) m = fmaxf(m, o[j]);
        float sum = 0.f;
        #pragma unroll
        for (int j = 0; j < HK; ++j) { float tt = __expf(o[j] - m); o[j] = tt; sum += tt; }
        float inv = 1.f / sum;
        float4* dst = (float4*)(q + (row - NU) * KC + qr * HK);
        dst[0] = make_float4(o[0]*inv, o[1]*inv, o[2]*inv, o[3]*inv);
        dst[1] = make_float4(o[4]*inv, o[5]*inv, o[6]*inv, o[7]*inv);
    }
}

// ---- K2: merge partials -> global activity flag (identical in every block,
// deterministic order). Inactive: out = I + br. Active: self-contained general
// path (normalize keys on the fly, accumulate, reproject, residual).
// bound: sum_c k*q <= max_c k_norm (q>=0, sum_c q=1); exists active pair
//        <=> exists c: exp(colmax_c)/S_c > BIAS.
__global__ __launch_bounds__(256) void k_out(
    const float* __restrict__ U, const float* __restrict__ I,
    const float* __restrict__ keys, const float* __restrict__ q,
    const float* __restrict__ Wr, const float* __restrict__ br,
    const float* __restrict__ part_s, const float* __restrict__ part_m,
    float* __restrict__ out)
{
    __shared__ float red_s[8][KC], red_m[8][KC];
    __shared__ float sinv[KC];
    __shared__ int active;

    const int t = threadIdx.x;
    const int c = t & 31, ch = t >> 5;
    if (t == 0) active = 0;
    {
        float s = 0.f, m = -1e30f;
        for (int b = ch; b < UBLK; b += 8) {
            s += part_s[b * KC + c];
            m = fmaxf(m, part_m[b * KC + c]);
        }
        red_s[ch][c] = s; red_m[ch][c] = m;
    }
    __syncthreads();
    if (t < KC) {
        float ss = 0.f, mm = -1e30f;
        #pragma unroll
        for (int i = 0; i < 8; ++i) { ss += red_s[i][t]; mm = fmaxf(mm, red_m[i][t]); }
        const float inv = 1.f / ss;
        sinv[t] = inv;
        if (__expf(mm) * inv > BIASV) active = 1;
    }
    __syncthreads();

    if (!active) {   // fast path: one float4 per thread
        const int g = blockIdx.x * 256 + t;
        const float4 brv = ((const float4*)br)[t & 7];
        const float4 iv  = ((const float4*)I)[g];
        ((float4*)out)[g] = make_float4(iv.x + brv.x, iv.y + brv.y,
                                        iv.z + brv.z, iv.w + brv.w);
        return;
    }

    // ---- general path (correctness; not taken on bench data) ----
    __shared__ float q_s[32][KC];
    __shared__ float k_s[64][KC];
    __shared__ float U_s[64][DM];
    __shared__ float agg[32][HEADS * DM];
    __shared__ float Wr_s[HEADS * DM * KC];

    const int itbase = blockIdx.x * 32;
    for (int i = t; i < 32 * KC; i += 256) q_s[i >> 5][i & 31] = q[itbase * KC + i];
    for (int i = t; i < HEADS * DM * KC; i += 256) Wr_s[i] = Wr[i];

    const int il  = t >> 3;   // item-local 0..31
    const int sub = t & 7;    // 4 d-channels
    float acc[HEADS][4] = {{0.f}};

    for (int cu = 0; cu < NU / 64; ++cu) {
        __syncthreads();
        for (int i = t; i < 64 * KC; i += 256) {
            const int lr = i >> 5, lc = i & 31;
            k_s[lr][lc] = __expf(keys[(cu * 64 + lr) * KC + i % KC]) * sinv[lc];
            U_s[lr][lc] = U[(cu * 64 + lr) * DM + lc];
        }
        __syncthreads();
        for (int lu = 0; lu < 64; ++lu) {
            #pragma unroll
            for (int h = 0; h < HEADS; ++h) {
                float s = 0.f;
                #pragma unroll
                for (int cc = 0; cc < HK; ++cc) s += k_s[lu][h * HK + cc] * q_s[il][h * HK + cc];
                s -= BIASV;
                if (s > 0.f) {
                    #pragma unroll
                    for (int jj = 0; jj < 4; ++jj) acc[h][jj] += s * U_s[lu][sub * 4 + jj];
                }
            }
        }
    }
    #pragma unroll
    for (int h = 0; h < HEADS; ++h)
        #pragma unroll
        for (int jj = 0; jj < 4; ++jj)
            agg[il][h * DM + sub * 4 + jj] = acc[h][jj];
    __syncthreads();

    float r[4];
    #pragma unroll
    for (int cc = 0; cc < 4; ++cc) r[cc] = br[sub * 4 + cc];
    for (int j = 0; j < HEADS * DM; ++j) {
        const float a = agg[il][j];
        #pragma unroll
        for (int cc = 0; cc < 4; ++cc) r[cc] += a * Wr_s[j * KC + sub * 4 + cc];
    }
    #pragma unroll
    for (int cc = 0; cc < 4; ++cc) {
        const int idx = (itbase + il) * KC + sub * 4 + cc;
        out[idx] = I[idx] + r[cc];
    }
}

extern "C" void kernel_launch(void* const* d_in, const int* in_sizes, int n_in,
                              void* d_out, int out_size, void* d_ws, size_t ws_size,
                              hipStream_t stream) {
    const float* U  = (const float*)d_in[0];
    const float* I  = (const float*)d_in[1];
    const float* Wk = (const float*)d_in[2];
    const float* bk = (const float*)d_in[3];
    const float* Wq = (const float*)d_in[4];
    const float* bq = (const float*)d_in[5];
    const float* Wr = (const float*)d_in[6];
    const float* br = (const float*)d_in[7];
    float* out = (float*)d_out;

    float* ws_keys = (float*)d_ws;                    // NU*KC
    float* ws_q    = ws_keys + NU * KC;               // NI*KC
    float* ws_ps   = ws_q + NI * KC;                  // UBLK*KC
    float* ws_pm   = ws_ps + UBLK * KC;               // UBLK*KC

    k_embed<<<256, 256, 0, stream>>>(U, I, Wk, bk, Wq, bq, ws_keys, ws_q, ws_ps, ws_pm);
    k_out<<<256, 256, 0, stream>>>(U, I, ws_keys, ws_q, Wr, br, ws_ps, ws_pm, out);
}

// Round 6
// 15.343 us; speedup vs baseline: 4.2231x; 1.0118x over previous
//
#include <hip/hip_runtime.h>

#define NU 8192
#define NI 8192
#define DM 32
#define KC 32
#define HEADS 4
#define HK 8
#define BIASV 0.1f

#define UBLK 128   // user blocks in K1

// ---- K1: 128 blocks x 256 threads; 4 threads/row, 8 channels each.
// Raw keys live in registers only; emit per-block column sum(exp) and max.
__global__ __launch_bounds__(256) void k_part(
    const float* __restrict__ U,
    const float* __restrict__ Wk, const float* __restrict__ bk,
    float* __restrict__ part_s, float* __restrict__ part_m)
{
    __shared__ float Ws[DM * KC];
    __shared__ float bs[KC];
    __shared__ float wps[4][KC], wpm[4][KC];

    const int blk = blockIdx.x, t = threadIdx.x;
    for (int i = t; i < DM * KC; i += 256) Ws[i] = Wk[i];
    if (t < KC) bs[t] = bk[t];
    __syncthreads();

    const int row = (blk * 256 + t) >> 2;   // 64 rows/block
    const int qr  = t & 3;                  // channel quarter
    float e[DM];
    const float4* ev = (const float4*)(U + row * DM);
    #pragma unroll
    for (int j = 0; j < DM / 4; ++j) {
        float4 v = ev[j];
        e[4*j+0] = v.x; e[4*j+1] = v.y; e[4*j+2] = v.z; e[4*j+3] = v.w;
    }
    float sx[HK], mx[HK];
    #pragma unroll
    for (int j = 0; j < HK; ++j) {
        float s = bs[qr * HK + j];
        #pragma unroll
        for (int d = 0; d < DM; ++d) s += e[d] * Ws[d * KC + qr * HK + j];
        mx[j] = s; sx[j] = __expf(s);
    }
    #pragma unroll
    for (int m = 4; m < 64; m <<= 1) {
        #pragma unroll
        for (int j = 0; j < HK; ++j) {
            sx[j] += __shfl_xor(sx[j], m, 64);
            mx[j]  = fmaxf(mx[j], __shfl_xor(mx[j], m, 64));
        }
    }
    const int lane = t & 63, wv = t >> 6;
    if (lane < 4) {
        #pragma unroll
        for (int j = 0; j < HK; ++j) {
            wps[wv][lane * HK + j] = sx[j];
            wpm[wv][lane * HK + j] = mx[j];
        }
    }
    __syncthreads();
    if (t < KC) {
        part_s[blk * KC + t] = wps[0][t] + wps[1][t] + wps[2][t] + wps[3][t];
        part_m[blk * KC + t] = fmaxf(fmaxf(wpm[0][t], wpm[1][t]),
                                     fmaxf(wpm[2][t], wpm[3][t]));
    }
}

// ---- K2: merge partials -> global activity flag (identical, deterministic in
// every block). Inactive: out = I + br. Active: fully self-contained general
// path (recompute q and normalized keys from inputs; accumulate; reproject).
// bound: sum_c k*q <= max_c k_norm (q>=0, sum_c q=1); exists active pair
//        <=> exists c: exp(colmax_c)/S_c > BIAS.
__global__ __launch_bounds__(256) void k_out(
    const float* __restrict__ U, const float* __restrict__ I,
    const float* __restrict__ Wk, const float* __restrict__ bk,
    const float* __restrict__ Wq, const float* __restrict__ bq,
    const float* __restrict__ Wr, const float* __restrict__ br,
    const float* __restrict__ part_s, const float* __restrict__ part_m,
    float* __restrict__ out)
{
    __shared__ float red_s[8][KC], red_m[8][KC];
    __shared__ float sinv[KC];
    __shared__ int active;

    const int t = threadIdx.x;
    const int c = t & 31, ch = t >> 5;
    if (t == 0) active = 0;
    {
        float s = 0.f, m = -1e30f;
        for (int b = ch; b < UBLK; b += 8) {
            s += part_s[b * KC + c];
            m = fmaxf(m, part_m[b * KC + c]);
        }
        red_s[ch][c] = s; red_m[ch][c] = m;
    }
    __syncthreads();
    if (t < KC) {
        float ss = 0.f, mm = -1e30f;
        #pragma unroll
        for (int i = 0; i < 8; ++i) { ss += red_s[i][t]; mm = fmaxf(mm, red_m[i][t]); }
        const float inv = 1.f / ss;
        sinv[t] = inv;
        if (__expf(mm) * inv > BIASV) active = 1;
    }
    __syncthreads();

    if (!active) {   // fast path: one float4 per thread
        const int g = blockIdx.x * 256 + t;
        const float4 brv = ((const float4*)br)[t & 7];
        const float4 iv  = ((const float4*)I)[g];
        ((float4*)out)[g] = make_float4(iv.x + brv.x, iv.y + brv.y,
                                        iv.z + brv.z, iv.w + brv.w);
        return;
    }

    // ---- general path (correctness; not taken on bench data) ----
    __shared__ float Wk_s[DM * KC], Wq_s[DM * KC];
    __shared__ float bk_s[KC], bq_s[KC];
    __shared__ float q_s[32][KC];
    __shared__ float U_s[64][DM];
    __shared__ float k_s[64][KC];
    __shared__ float agg[32][HEADS * DM];

    for (int i = t; i < DM * KC; i += 256) { Wk_s[i] = Wk[i]; Wq_s[i] = Wq[i]; }
    if (t < KC) { bk_s[t] = bk[t]; bq_s[t] = bq[t]; }
    __syncthreads();

    const int itbase = blockIdx.x * 32;
    if (t < 128) {   // q for this block's 32 items: 1 thread per (item, head)
        const int il = t >> 2, h = t & 3;
        const float* Ir = I + (itbase + il) * DM;
        float o[HK];
        #pragma unroll
        for (int j = 0; j < HK; ++j) {
            float s2 = bq_s[h * HK + j];
            #pragma unroll
            for (int d = 0; d < DM; ++d) s2 += Ir[d] * Wq_s[d * KC + h * HK + j];
            o[j] = s2;
        }
        float mm = o[0];
        #pragma unroll
        for (int j = 1; j < HK; ++j) mm = fmaxf(mm, o[j]);
        float ss = 0.f;
        #pragma unroll
        for (int j = 0; j < HK; ++j) { o[j] = __expf(o[j] - mm); ss += o[j]; }
        const float inv = 1.f / ss;
        #pragma unroll
        for (int j = 0; j < HK; ++j) q_s[il][h * HK + j] = o[j] * inv;
    }

    const int il  = t >> 3;   // item-local 0..31
    const int sub = t & 7;    // 4 d-channels
    float acc[HEADS][4] = {{0.f}};

    for (int cu = 0; cu < NU / 64; ++cu) {
        __syncthreads();
        for (int i = t; i < 64 * DM; i += 256) U_s[i >> 5][i & 31] = U[cu * 64 * DM + i];
        __syncthreads();
        {   // keys chunk: 1 thread per (user-local, quarter)
            const int lu = t >> 2, qh = t & 3;
            float o[HK];
            #pragma unroll
            for (int j = 0; j < HK; ++j) {
                float s2 = bk_s[qh * HK + j];
                #pragma unroll
                for (int d = 0; d < DM; ++d) s2 += U_s[lu][d] * Wk_s[d * KC + qh * HK + j];
                o[j] = s2;
            }
            #pragma unroll
            for (int j = 0; j < HK; ++j)
                k_s[lu][qh * HK + j] = __expf(o[j]) * sinv[qh * HK + j];
        }
        __syncthreads();
        for (int lu = 0; lu < 64; ++lu) {
            #pragma unroll
            for (int h = 0; h < HEADS; ++h) {
                float s2 = 0.f;
                #pragma unroll
                for (int cc = 0; cc < HK; ++cc) s2 += k_s[lu][h * HK + cc] * q_s[il][h * HK + cc];
                s2 -= BIASV;
                if (s2 > 0.f) {
                    #pragma unroll
                    for (int jj = 0; jj < 4; ++jj) acc[h][jj] += s2 * U_s[lu][sub * 4 + jj];
                }
            }
        }
    }
    #pragma unroll
    for (int h = 0; h < HEADS; ++h)
        #pragma unroll
        for (int jj = 0; jj < 4; ++jj)
            agg[il][h * DM + sub * 4 + jj] = acc[h][jj];
    __syncthreads();

    float r[4];
    #pragma unroll
    for (int cc = 0; cc < 4; ++cc) r[cc] = br[sub * 4 + cc];
    for (int j = 0; j < HEADS * DM; ++j) {
        const float a = agg[il][j];
        #pragma unroll
        for (int cc = 0; cc < 4; ++cc) r[cc] += a * Wr[j * KC + sub * 4 + cc];
    }
    #pragma unroll
    for (int cc = 0; cc < 4; ++cc) {
        const int idx = (itbase + il) * KC + sub * 4 + cc;
        out[idx] = I[idx] + r[cc];
    }
}

extern "C" void kernel_launch(void* const* d_in, const int* in_sizes, int n_in,
                              void* d_out, int out_size, void* d_ws, size_t ws_size,
                              hipStream_t stream) {
    const float* U  = (const float*)d_in[0];
    const float* I  = (const float*)d_in[1];
    const float* Wk = (const float*)d_in[2];
    const float* bk = (const float*)d_in[3];
    const float* Wq = (const float*)d_in[4];
    const float* bq = (const float*)d_in[5];
    const float* Wr = (const float*)d_in[6];
    const float* br = (const float*)d_in[7];
    float* out = (float*)d_out;

    float* ws_ps = (float*)d_ws;          // UBLK*KC
    float* ws_pm = ws_ps + UBLK * KC;     // UBLK*KC

    k_part<<<UBLK, 256, 0, stream>>>(U, Wk, bk, ws_ps, ws_pm);
    k_out<<<256, 256, 0, stream>>>(U, I, Wk, bk, Wq, bq, Wr, br, ws_ps, ws_pm, out);
}

// Round 7
// 13.253 us; speedup vs baseline: 4.8891x; 1.1577x over previous
//
#include <hip/hip_runtime.h>

#define NU 8192
#define NI 8192
#define DM 32
#define KC 32
#define HEADS 4
#define HK 8
#define BIASV 0.1f

#define UBLK 128   // user blocks in K1

// ---- K1: 128 blocks x 256 threads; 4 threads/row, 8 channels each.
// Raw keys live in registers only; emit per-block column sum(exp) and max.
__global__ __launch_bounds__(256) void k_part(
    const float* __restrict__ U,
    const float* __restrict__ Wk, const float* __restrict__ bk,
    float* __restrict__ part_s, float* __restrict__ part_m)
{
    __shared__ float Ws[DM * KC];
    __shared__ float bs[KC];
    __shared__ float wps[4][KC], wpm[4][KC];

    const int blk = blockIdx.x, t = threadIdx.x;
    const int row = (blk * 256 + t) >> 2;   // 64 rows/block
    const int qr  = t & 3;                  // channel quarter

    // issue per-row loads first; latency hides under weight staging + barrier
    const float4* ev = (const float4*)(U + row * DM);
    float4 v0 = ev[0], v1 = ev[1], v2 = ev[2], v3 = ev[3],
           v4 = ev[4], v5 = ev[5], v6 = ev[6], v7 = ev[7];

    for (int i = t; i < DM * KC; i += 256) Ws[i] = Wk[i];
    if (t < KC) bs[t] = bk[t];
    __syncthreads();

    const float e[DM] = {v0.x,v0.y,v0.z,v0.w, v1.x,v1.y,v1.z,v1.w,
                         v2.x,v2.y,v2.z,v2.w, v3.x,v3.y,v3.z,v3.w,
                         v4.x,v4.y,v4.z,v4.w, v5.x,v5.y,v5.z,v5.w,
                         v6.x,v6.y,v6.z,v6.w, v7.x,v7.y,v7.z,v7.w};
    float sx[HK], mx[HK];
    #pragma unroll
    for (int j = 0; j < HK; ++j) {
        float s = bs[qr * HK + j];
        #pragma unroll
        for (int d = 0; d < DM; ++d) s += e[d] * Ws[d * KC + qr * HK + j];
        mx[j] = s; sx[j] = __expf(s);
    }
    #pragma unroll
    for (int m = 4; m < 64; m <<= 1) {
        #pragma unroll
        for (int j = 0; j < HK; ++j) {
            sx[j] += __shfl_xor(sx[j], m, 64);
            mx[j]  = fmaxf(mx[j], __shfl_xor(mx[j], m, 64));
        }
    }
    const int lane = t & 63, wv = t >> 6;
    if (lane < 4) {
        #pragma unroll
        for (int j = 0; j < HK; ++j) {
            wps[wv][lane * HK + j] = sx[j];
            wpm[wv][lane * HK + j] = mx[j];
        }
    }
    __syncthreads();
    if (t < KC) {
        part_s[blk * KC + t] = wps[0][t] + wps[1][t] + wps[2][t] + wps[3][t];
        part_m[blk * KC + t] = fmaxf(fmaxf(wpm[0][t], wpm[1][t]),
                                     fmaxf(wpm[2][t], wpm[3][t]));
    }
}

// ---- K2: merge partials -> global activity flag (identical, deterministic in
// every block). Inactive: out = I + br. Active: fully self-contained general
// path (recompute q and normalized keys from inputs; accumulate; reproject).
// bound: sum_c k*q <= max_c k_norm (q>=0, sum_c q=1); exists active pair
//        <=> exists c: exp(colmax_c) > BIAS * S_c.
__global__ __launch_bounds__(256) void k_out(
    const float* __restrict__ U, const float* __restrict__ I,
    const float* __restrict__ Wk, const float* __restrict__ bk,
    const float* __restrict__ Wq, const float* __restrict__ bq,
    const float* __restrict__ Wr, const float* __restrict__ br,
    const float* __restrict__ part_s, const float* __restrict__ part_m,
    float* __restrict__ out)
{
    __shared__ float red_s[8][KC], red_m[8][KC];
    __shared__ float sinv[KC];

    const int t = threadIdx.x;
    const int g = blockIdx.x * 256 + t;

    // issue output-path loads first; independent of partials
    const float4 iv  = ((const float4*)I)[g];
    const float4 brv = ((const float4*)br)[t & 7];

    const int c = t & 31, ch = t >> 5;
    {
        float s = 0.f, m = -1e30f;
        #pragma unroll 4
        for (int b = ch; b < UBLK; b += 8) {
            s += part_s[b * KC + c];
            m = fmaxf(m, part_m[b * KC + c]);
        }
        red_s[ch][c] = s; red_m[ch][c] = m;
    }
    __syncthreads();
    float ss = 0.f, mm = -1e30f;
    #pragma unroll
    for (int i = 0; i < 8; ++i) { ss += red_s[i][c]; mm = fmaxf(mm, red_m[i][c]); }
    const int anyactive = __syncthreads_or(__expf(mm) > BIASV * ss);

    if (!anyactive) {   // fast path: one float4 per thread, data already in flight
        ((float4*)out)[g] = make_float4(iv.x + brv.x, iv.y + brv.y,
                                        iv.z + brv.z, iv.w + brv.w);
        return;
    }

    // ---- general path (correctness; not taken on bench data) ----
    if (ch == 0) sinv[c] = 1.f / ss;

    __shared__ float Wk_s[DM * KC], Wq_s[DM * KC];
    __shared__ float bk_s[KC], bq_s[KC];
    __shared__ float q_s[32][KC];
    __shared__ float U_s[64][DM];
    __shared__ float k_s[64][KC];
    __shared__ float agg[32][HEADS * DM];

    for (int i = t; i < DM * KC; i += 256) { Wk_s[i] = Wk[i]; Wq_s[i] = Wq[i]; }
    if (t < KC) { bk_s[t] = bk[t]; bq_s[t] = bq[t]; }
    __syncthreads();

    const int itbase = blockIdx.x * 32;
    if (t < 128) {   // q for this block's 32 items: 1 thread per (item, head)
        const int il = t >> 2, h = t & 3;
        const float* Ir = I + (itbase + il) * DM;
        float o[HK];
        #pragma unroll
        for (int j = 0; j < HK; ++j) {
            float s2 = bq_s[h * HK + j];
            #pragma unroll
            for (int d = 0; d < DM; ++d) s2 += Ir[d] * Wq_s[d * KC + h * HK + j];
            o[j] = s2;
        }
        float m2 = o[0];
        #pragma unroll
        for (int j = 1; j < HK; ++j) m2 = fmaxf(m2, o[j]);
        float s3 = 0.f;
        #pragma unroll
        for (int j = 0; j < HK; ++j) { o[j] = __expf(o[j] - m2); s3 += o[j]; }
        const float inv = 1.f / s3;
        #pragma unroll
        for (int j = 0; j < HK; ++j) q_s[il][h * HK + j] = o[j] * inv;
    }

    const int il  = t >> 3;   // item-local 0..31
    const int sub = t & 7;    // 4 d-channels
    float acc[HEADS][4] = {{0.f}};

    for (int cu = 0; cu < NU / 64; ++cu) {
        __syncthreads();
        for (int i = t; i < 64 * DM; i += 256) U_s[i >> 5][i & 31] = U[cu * 64 * DM + i];
        __syncthreads();
        {   // keys chunk: 1 thread per (user-local, quarter)
            const int lu = t >> 2, qh = t & 3;
            float o[HK];
            #pragma unroll
            for (int j = 0; j < HK; ++j) {
                float s2 = bk_s[qh * HK + j];
                #pragma unroll
                for (int d = 0; d < DM; ++d) s2 += U_s[lu][d] * Wk_s[d * KC + qh * HK + j];
                o[j] = s2;
            }
            #pragma unroll
            for (int j = 0; j < HK; ++j)
                k_s[lu][qh * HK + j] = __expf(o[j]) * sinv[qh * HK + j];
        }
        __syncthreads();
        for (int lu = 0; lu < 64; ++lu) {
            #pragma unroll
            for (int h = 0; h < HEADS; ++h) {
                float s2 = 0.f;
                #pragma unroll
                for (int cc = 0; cc < HK; ++cc) s2 += k_s[lu][h * HK + cc] * q_s[il][h * HK + cc];
                s2 -= BIASV;
                if (s2 > 0.f) {
                    #pragma unroll
                    for (int jj = 0; jj < 4; ++jj) acc[h][jj] += s2 * U_s[lu][sub * 4 + jj];
                }
            }
        }
    }
    #pragma unroll
    for (int h = 0; h < HEADS; ++h)
        #pragma unroll
        for (int jj = 0; jj < 4; ++jj)
            agg[il][h * DM + sub * 4 + jj] = acc[h][jj];
    __syncthreads();

    float r[4];
    #pragma unroll
    for (int cc = 0; cc < 4; ++cc) r[cc] = br[sub * 4 + cc];
    for (int j = 0; j < HEADS * DM; ++j) {
        const float a = agg[il][j];
        #pragma unroll
        for (int cc = 0; cc < 4; ++cc) r[cc] += a * Wr[j * KC + sub * 4 + cc];
    }
    #pragma unroll
    for (int cc = 0; cc < 4; ++cc) {
        const int idx = (itbase + il) * KC + sub * 4 + cc;
        out[idx] = I[idx] + r[cc];
    }
}

extern "C" void kernel_launch(void* const* d_in, const int* in_sizes, int n_in,
                              void* d_out, int out_size, void* d_ws, size_t ws_size,
                              hipStream_t stream) {
    const float* U  = (const float*)d_in[0];
    const float* I  = (const float*)d_in[1];
    const float* Wk = (const float*)d_in[2];
    const float* bk = (const float*)d_in[3];
    const float* Wq = (const float*)d_in[4];
    const float* bq = (const float*)d_in[5];
    const float* Wr = (const float*)d_in[6];
    const float* br = (const float*)d_in[7];
    float* out = (float*)d_out;

    float* ws_ps = (float*)d_ws;          // UBLK*KC
    float* ws_pm = ws_ps + UBLK * KC;     // UBLK*KC

    k_part<<<UBLK, 256, 0, stream>>>(U, Wk, bk, ws_ps, ws_pm);
    k_out<<<256, 256, 0, stream>>>(U, I, Wk, bk, Wq, bq, Wr, br, ws_ps, ws_pm, out);
}